// Round 6
// baseline (315.329 us; speedup 1.0000x reference)
//
#include <hip/hip_runtime.h>
#include <stdint.h>

// Problem constants (B,S,D,H fixed by the reference)
#define SEQ 1568
#define SEQV 1600   // vtb padded s-stride: 1600*2B = 25 full 128B lines
#define DIM 1024
#define NB 4
#define NH 16
#define HD 64

typedef unsigned short u16;
typedef __bf16 bf16x8 __attribute__((ext_vector_type(8)));
typedef float f32x4 __attribute__((ext_vector_type(4)));

// log2(e)/8: folded into q so QK^T scores come out in exp2 domain
#define QSCALE 0.18033688011112042f

// sP row stride (u16). MUST be >= 64 (P tile is 32 x 64); 72 = 64 + 8 pad
// breaks the power-of-2-stride conflicts. (R4's 44 corrupted sP.)
#define PSTR 72

// async global->LDS, 16B per lane. LDS dest is wave-uniform base + lane*16.
__device__ __forceinline__ void load_lds16(const u16* g, u16* s) {
  __builtin_amdgcn_global_load_lds((__attribute__((address_space(1))) void*)g,
                                   (__attribute__((address_space(3))) void*)s,
                                   16, 0, 0);
}

// ---------------------------------------------------------------------------
// Fused fp32 -> bf16 convert of x + all 4 weights (one launch, 4 elems/thread)
// ---------------------------------------------------------------------------
__global__ __launch_bounds__(256) void cvt_all(
    const float* __restrict__ x,  const float* __restrict__ wq,
    const float* __restrict__ wk, const float* __restrict__ wv,
    const float* __restrict__ wp,
    u16* __restrict__ xb, u16* __restrict__ wqb, u16* __restrict__ wkb,
    u16* __restrict__ wvb, u16* __restrict__ wpb) {
  int i = blockIdx.x * 256 + threadIdx.x;   // grid sized exactly: 2654208 total
  const float* src; u16* dst; int off;
  if (i < 1605632)      { src = x;  dst = xb;  off = i; }
  else if (i < 1867776) { src = wq; dst = wqb; off = i - 1605632; }
  else if (i < 2129920) { src = wk; dst = wkb; off = i - 1867776; }
  else if (i < 2392064) { src = wv; dst = wvb; off = i - 2129920; }
  else                  { src = wp; dst = wpb; off = i - 2392064; }
  float4 v = ((const float4*)src)[off];
  union { unsigned long long u; __bf16 h[4]; } o;
  o.h[0] = (__bf16)v.x; o.h[1] = (__bf16)v.y;
  o.h[2] = (__bf16)v.z; o.h[3] = (__bf16)v.w;
  ((unsigned long long*)dst)[off] = o.u;
}

// ---------------------------------------------------------------------------
// QKV projection GEMM, BK=64: C[m,n] = sum_k X[m,k] * W[n,k] + bias[n]
// 16 K-iterations (was 32) -> half the vmcnt(0)+barrier drains, 32 MFMA per
// drain. sA/sB rows are 64 elems (128B) with XOR chunk swizzle: phys slot p
// of row r holds logical chunk p^(r&7) -> b128 fragment reads are
// bank-uniform. Blocks never straddle a batch boundary; vtb rows padded to
// SEQV -> every 128B output line written by one block (no cross-XCD false
// sharing — the R2 lesson).
// ---------------------------------------------------------------------------
__global__ __launch_bounds__(256) void gemm_qkv(
    const u16* __restrict__ xb,
    const u16* __restrict__ wq, const u16* __restrict__ wk, const u16* __restrict__ wv,
    const float* __restrict__ bq, const float* __restrict__ bk, const float* __restrict__ bv,
    u16* __restrict__ qo, u16* __restrict__ ko, u16* __restrict__ vto) {
  const int z = blockIdx.z;
  const u16* W = (z == 0) ? wq : (z == 1) ? wk : wv;
  const float* bias = (z == 0) ? bq : (z == 1) ? bk : bv;

  __shared__ __align__(16) u16 sA[128 * 64];
  __shared__ __align__(16) u16 sB[128 * 64];

  const int tid = threadIdx.x;
  const int wave = tid >> 6;
  const int lane = tid & 63;
  const int l15 = lane & 15;
  const int quad = lane >> 4;
  const int bi = blockIdx.y / 13;        // batch
  const int st = blockIdx.y % 13;        // s-tile within batch (tile 12: 32 rows)
  const int bn = blockIdx.x * 128;
  const int wm = (wave >> 1) * 64;
  const int wn = (wave & 1) * 64;

  const int jrow = lane >> 3;            // 0..7
  const int cg = (lane & 7) ^ jrow;      // xor-swizzled chunk to fetch
  const int j7 = l15 & 7;
  const int r0 = wave * 32;              // this wave's staging rows

  f32x4 acc[4][4] = {};

  for (int k0 = 0; k0 < DIM; k0 += 64) {
    __syncthreads();
#pragma unroll
    for (int i = 0; i < 4; i++) {
      int srow = st * 128 + r0 + i * 8 + jrow;
      if (srow >= SEQ) srow = SEQ - 1;   // clamp for the partial tail tile
      load_lds16(xb + (size_t)(bi * SEQ + srow) * DIM + k0 + cg * 8,
                 &sA[(r0 + i * 8) * 64]);
    }
#pragma unroll
    for (int i = 0; i < 4; i++)
      load_lds16(W + (size_t)(bn + r0 + i * 8 + jrow) * DIM + k0 + cg * 8,
                 &sB[(r0 + i * 8) * 64]);
    __syncthreads();

    bf16x8 a[2][4], b[2][4];
#pragma unroll
    for (int kk = 0; kk < 2; kk++) {
#pragma unroll
      for (int mt = 0; mt < 4; mt++)
        a[kk][mt] = *(const bf16x8*)&sA[(wm + mt * 16 + l15) * 64 +
                                        (((kk * 4 + quad) ^ j7) * 8)];
#pragma unroll
      for (int nt = 0; nt < 4; nt++)
        b[kk][nt] = *(const bf16x8*)&sB[(wn + nt * 16 + l15) * 64 +
                                        (((kk * 4 + quad) ^ j7) * 8)];
    }
#pragma unroll
    for (int kk = 0; kk < 2; kk++)
#pragma unroll
      for (int mt = 0; mt < 4; mt++)
#pragma unroll
        for (int nt = 0; nt < 4; nt++)
          acc[mt][nt] = __builtin_amdgcn_mfma_f32_16x16x32_bf16(
              a[kk][mt], b[kk][nt], acc[mt][nt], 0, 0, 0);
  }

  // epilogue: C/D layout col=lane&15, row=quad*4+reg
#pragma unroll
  for (int nt = 0; nt < 4; nt++) {
    const int n = bn + wn + nt * 16 + l15;
    const float bia = bias[n];
    const int h = n >> 6, d = n & 63;
#pragma unroll
    for (int mt = 0; mt < 4; mt++) {
      const int sbase = st * 128 + wm + mt * 16 + quad * 4;
#pragma unroll
      for (int r = 0; r < 4; r++) {
        const int s = sbase + r;
        if (s < SEQ) {
          float val = acc[mt][nt][r] + bia;
          if (z == 0) val *= QSCALE;
          const __bf16 o = (__bf16)val;
          if (z == 0)
            *(__bf16*)&qo[(((size_t)(bi * NH + h)) * SEQ + s) * HD + d] = o;
          else if (z == 1)
            *(__bf16*)&ko[(((size_t)(bi * NH + h)) * SEQ + s) * HD + d] = o;
          else
            *(__bf16*)&vto[(((size_t)(bi * NH + h)) * HD + d) * SEQV + s] = o;
        }
      }
    }
  }
}

// ---------------------------------------------------------------------------
// Flash attention (unchanged from R5-pass): no-max exp2-domain softmax,
// 4 waves x 32 q-rows, j-tiles of 64, 24 clean tiles + explicit 32-j tail.
// ---------------------------------------------------------------------------
__global__ __launch_bounds__(256, 4) void attn(
    const u16* __restrict__ q, const u16* __restrict__ k,
    const u16* __restrict__ vt, u16* __restrict__ ctx) {
  const int bh = blockIdx.y;   // 0..63 (b*16+h)
  const int qt = blockIdx.x;   // 0..12, 128 q-rows each
  const int tid = threadIdx.x;
  const int wave = tid >> 6, lane = tid & 63, l15 = lane & 15, quad = lane >> 4;

  __shared__ __align__(16) u16 sK[64 * 64];        // [j][d], chunk-swizzled
  __shared__ __align__(16) u16 sV[64 * 64];        // [d][j], chunk-swizzled
  __shared__ __align__(16) u16 sP[4][32 * PSTR];   // per-wave P [i][j]

  const u16* qh = q + (size_t)bh * (SEQ * HD);
  const u16* kh = k + (size_t)bh * (SEQ * HD);
  const u16* vh = vt + (size_t)bh * (HD * SEQV);

  bf16x8 aq[2][2];
#pragma unroll
  for (int mt = 0; mt < 2; mt++) {
    int qrow = qt * 128 + wave * 32 + mt * 16 + l15;
    int qr = qrow < SEQ ? qrow : SEQ - 1;
    aq[mt][0] = *(const bf16x8*)&qh[(size_t)qr * HD + quad * 8];
    aq[mt][1] = *(const bf16x8*)&qh[(size_t)qr * HD + 32 + quad * 8];
  }

  f32x4 o[2][4] = {};
  float lrow[2][4] = {};

  const int jrow = lane >> 3;
  const int cg = (lane & 7) ^ jrow;
  u16* sPw = sP[wave];
  const int j7 = l15 & 7;

  // ---- 24 full 64-j tiles ----
  for (int j0 = 0; j0 < 1536; j0 += 64) {
    __syncthreads();
    load_lds16(&kh[(size_t)(j0 + wave * 16 + jrow) * HD + cg * 8], &sK[(wave * 16) * 64]);
    load_lds16(&kh[(size_t)(j0 + wave * 16 + 8 + jrow) * HD + cg * 8], &sK[(wave * 16 + 8) * 64]);
    load_lds16(&vh[(size_t)(wave * 16 + jrow) * SEQV + j0 + cg * 8], &sV[(wave * 16) * 64]);
    load_lds16(&vh[(size_t)(wave * 16 + 8 + jrow) * SEQV + j0 + cg * 8], &sV[(wave * 16 + 8) * 64]);
    __syncthreads();

#pragma unroll
    for (int mt = 0; mt < 2; mt++) {
      f32x4 s[4];
#pragma unroll
      for (int jt = 0; jt < 4; jt++) {
        const int j = jt * 16 + l15;
        bf16x8 b0 = *(const bf16x8*)&sK[j * 64 + ((quad ^ j7) * 8)];
        bf16x8 b1 = *(const bf16x8*)&sK[j * 64 + (((4 + quad) ^ j7) * 8)];
        f32x4 acc = {};
        acc = __builtin_amdgcn_mfma_f32_16x16x32_bf16(aq[mt][0], b0, acc, 0, 0, 0);
        acc = __builtin_amdgcn_mfma_f32_16x16x32_bf16(aq[mt][1], b1, acc, 0, 0, 0);
        s[jt] = acc;
      }
#pragma unroll
      for (int jt = 0; jt < 4; jt++)
#pragma unroll
        for (int r = 0; r < 4; r++) {
          float p = __builtin_exp2f(s[jt][r]);
          lrow[mt][r] += p;
          *(__bf16*)&sPw[(mt * 16 + quad * 4 + r) * PSTR + jt * 16 + l15] = (__bf16)p;
        }
    }

    asm volatile("s_waitcnt lgkmcnt(0)" ::: "memory");

#pragma unroll
    for (int kc = 0; kc < 2; kc++) {
      bf16x8 ap0 = *(const bf16x8*)&sPw[l15 * PSTR + kc * 32 + quad * 8];
      bf16x8 ap1 = *(const bf16x8*)&sPw[(16 + l15) * PSTR + kc * 32 + quad * 8];
#pragma unroll
      for (int dt = 0; dt < 4; dt++) {
        const int d7 = l15 & 7;
        bf16x8 bv = *(const bf16x8*)&sV[(dt * 16 + l15) * 64 + (((kc * 4 + quad) ^ d7) * 8)];
        o[0][dt] = __builtin_amdgcn_mfma_f32_16x16x32_bf16(ap0, bv, o[0][dt], 0, 0, 0);
        o[1][dt] = __builtin_amdgcn_mfma_f32_16x16x32_bf16(ap1, bv, o[1][dt], 0, 0, 0);
      }
    }
  }

  // ---- tail tile: j0 = 1536, 32 valid j (jt 0..1, kc 0) ----
  {
    const int j0 = 1536;
    __syncthreads();
    if (wave < 2) {
      load_lds16(&kh[(size_t)(j0 + wave * 16 + jrow) * HD + cg * 8], &sK[(wave * 16) * 64]);
      load_lds16(&kh[(size_t)(j0 + wave * 16 + 8 + jrow) * HD + cg * 8], &sK[(wave * 16 + 8) * 64]);
    }
    load_lds16(&vh[(size_t)(wave * 16 + jrow) * SEQV + j0 + cg * 8], &sV[(wave * 16) * 64]);
    load_lds16(&vh[(size_t)(wave * 16 + 8 + jrow) * SEQV + j0 + cg * 8], &sV[(wave * 16 + 8) * 64]);
    __syncthreads();

#pragma unroll
    for (int mt = 0; mt < 2; mt++) {
      f32x4 s[2];
#pragma unroll
      for (int jt = 0; jt < 2; jt++) {
        const int j = jt * 16 + l15;
        bf16x8 b0 = *(const bf16x8*)&sK[j * 64 + ((quad ^ j7) * 8)];
        bf16x8 b1 = *(const bf16x8*)&sK[j * 64 + (((4 + quad) ^ j7) * 8)];
        f32x4 acc = {};
        acc = __builtin_amdgcn_mfma_f32_16x16x32_bf16(aq[mt][0], b0, acc, 0, 0, 0);
        acc = __builtin_amdgcn_mfma_f32_16x16x32_bf16(aq[mt][1], b1, acc, 0, 0, 0);
        s[jt] = acc;
      }
#pragma unroll
      for (int jt = 0; jt < 2; jt++)
#pragma unroll
        for (int r = 0; r < 4; r++) {
          float p = __builtin_exp2f(s[jt][r]);
          lrow[mt][r] += p;
          *(__bf16*)&sPw[(mt * 16 + quad * 4 + r) * PSTR + jt * 16 + l15] = (__bf16)p;
        }
    }

    asm volatile("s_waitcnt lgkmcnt(0)" ::: "memory");

    {
      bf16x8 ap0 = *(const bf16x8*)&sPw[l15 * PSTR + quad * 8];
      bf16x8 ap1 = *(const bf16x8*)&sPw[(16 + l15) * PSTR + quad * 8];
#pragma unroll
      for (int dt = 0; dt < 4; dt++) {
        const int d7 = l15 & 7;
        bf16x8 bv = *(const bf16x8*)&sV[(dt * 16 + l15) * 64 + ((quad ^ d7) * 8)];
        o[0][dt] = __builtin_amdgcn_mfma_f32_16x16x32_bf16(ap0, bv, o[0][dt], 0, 0, 0);
        o[1][dt] = __builtin_amdgcn_mfma_f32_16x16x32_bf16(ap1, bv, o[1][dt], 0, 0, 0);
      }
    }
  }

  // epilogue
  const int bi = bh >> 4, h = bh & 15;
#pragma unroll
  for (int mt = 0; mt < 2; mt++) {
#pragma unroll
    for (int r = 0; r < 4; r++) {
      float l = lrow[mt][r];
#pragma unroll
      for (int off = 8; off >= 1; off >>= 1) l += __shfl_xor(l, off, 16);
      const int srow = qt * 128 + wave * 32 + mt * 16 + quad * 4 + r;
      if (srow < SEQ) {
        const float inv = 1.0f / l;
#pragma unroll
        for (int dt = 0; dt < 4; dt++)
          *(__bf16*)&ctx[((size_t)(bi * SEQ + srow)) * DIM + h * HD + dt * 16 + l15] =
              (__bf16)(o[mt][dt][r] * inv);
      }
    }
  }
}

// ---------------------------------------------------------------------------
// Output projection, BK=64, 64x128 tile: out = ctx @ Wp^T + bp, fp32 out.
// Grid (8, 98) = 784 blocks (~3/CU) — the 128-row version's 392 blocks left
// the second occupancy round half idle. 6272 = 98*64 exactly: no row masks.
// ---------------------------------------------------------------------------
__global__ __launch_bounds__(256) void gemm_out(
    const u16* __restrict__ ctx, const u16* __restrict__ wp,
    const float* __restrict__ bp, float* __restrict__ out) {
  __shared__ __align__(16) u16 sA[64 * 64];
  __shared__ __align__(16) u16 sB[128 * 64];

  const int tid = threadIdx.x;
  const int wave = tid >> 6;
  const int lane = tid & 63;
  const int l15 = lane & 15;
  const int quad = lane >> 4;
  const int bm = blockIdx.y * 64;
  const int bn = blockIdx.x * 128;
  const int wm = (wave >> 1) * 32;
  const int wn = (wave & 1) * 64;

  const int jrow = lane >> 3;
  const int cg = (lane & 7) ^ jrow;
  const int j7 = l15 & 7;
  const int r0a = wave * 16;
  const int r0b = wave * 32;

  f32x4 acc[2][4] = {};

  for (int k0 = 0; k0 < DIM; k0 += 64) {
    __syncthreads();
#pragma unroll
    for (int i = 0; i < 2; i++)
      load_lds16(ctx + (size_t)(bm + r0a + i * 8 + jrow) * DIM + k0 + cg * 8,
                 &sA[(r0a + i * 8) * 64]);
#pragma unroll
    for (int i = 0; i < 4; i++)
      load_lds16(wp + (size_t)(bn + r0b + i * 8 + jrow) * DIM + k0 + cg * 8,
                 &sB[(r0b + i * 8) * 64]);
    __syncthreads();

    bf16x8 a[2][2], b[2][4];
#pragma unroll
    for (int kk = 0; kk < 2; kk++) {
#pragma unroll
      for (int mt = 0; mt < 2; mt++)
        a[kk][mt] = *(const bf16x8*)&sA[(wm + mt * 16 + l15) * 64 +
                                        (((kk * 4 + quad) ^ j7) * 8)];
#pragma unroll
      for (int nt = 0; nt < 4; nt++)
        b[kk][nt] = *(const bf16x8*)&sB[(wn + nt * 16 + l15) * 64 +
                                        (((kk * 4 + quad) ^ j7) * 8)];
    }
#pragma unroll
    for (int kk = 0; kk < 2; kk++)
#pragma unroll
      for (int mt = 0; mt < 2; mt++)
#pragma unroll
        for (int nt = 0; nt < 4; nt++)
          acc[mt][nt] = __builtin_amdgcn_mfma_f32_16x16x32_bf16(
              a[kk][mt], b[kk][nt], acc[mt][nt], 0, 0, 0);
  }

#pragma unroll
  for (int nt = 0; nt < 4; nt++) {
    const int n = bn + wn + nt * 16 + l15;
    const float bia = bp[n];
#pragma unroll
    for (int mt = 0; mt < 2; mt++) {
      const int mbase = bm + wm + mt * 16 + quad * 4;
#pragma unroll
      for (int r = 0; r < 4; r++)
        out[(size_t)(mbase + r) * DIM + n] = acc[mt][nt][r] + bia;
    }
  }
}

// ---------------------------------------------------------------------------
// Workspace layout (bytes):
//  xb   @ 0         : 12,845,056  (x bf16)
//  wqb  @ 12845056  :  2,097,152
//  wkb  @ 14942208  :  2,097,152
//  wvb  @ 17039360  :  2,097,152
//  wpb  @ 19136512  :  2,097,152
//  qb   @ 21233664  : 12,845,056  ([B,H,S,HD] bf16, pre-scaled by QSCALE)
//  kb   @ 34078720  : 12,845,056  ([B,H,S,HD] bf16)
//  vtb  @ 46923776  : 13,107,200  ([B,H,HD,SEQV=1600] bf16, line-aligned rows)
//  ctxb @ 60030976  : 12,845,056  ([B,S,D] bf16)
//  total 72,876,032 bytes
// ---------------------------------------------------------------------------
extern "C" void kernel_launch(void* const* d_in, const int* in_sizes, int n_in,
                              void* d_out, int out_size, void* d_ws, size_t ws_size,
                              hipStream_t stream) {
  const float* x  = (const float*)d_in[0];
  const float* Wq = (const float*)d_in[1];
  const float* bq = (const float*)d_in[2];
  const float* Wk = (const float*)d_in[3];
  const float* bk = (const float*)d_in[4];
  const float* Wv = (const float*)d_in[5];
  const float* bv = (const float*)d_in[6];
  const float* Wp = (const float*)d_in[7];
  const float* bp = (const float*)d_in[8];
  float* out = (float*)d_out;

  char* ws = (char*)d_ws;
  u16* xb   = (u16*)(ws + 0);
  u16* wqb  = (u16*)(ws + 12845056);
  u16* wkb  = (u16*)(ws + 14942208);
  u16* wvb  = (u16*)(ws + 17039360);
  u16* wpb  = (u16*)(ws + 19136512);
  u16* qb   = (u16*)(ws + 21233664);
  u16* kb   = (u16*)(ws + 34078720);
  u16* vtb  = (u16*)(ws + 46923776);
  u16* ctxb = (u16*)(ws + 60030976);

  cvt_all<<<10368, 256, 0, stream>>>(x, Wq, Wk, Wv, Wp, xb, wqb, wkb, wvb, wpb);
  gemm_qkv<<<dim3(8, 52, 3), 256, 0, stream>>>(xb, wqb, wkb, wvb, bq, bk, bv, qb, kb, vtb);
  attn<<<dim3(13, 64), 256, 0, stream>>>(qb, kb, vtb, ctxb);
  gemm_out<<<dim3(8, 98), 256, 0, stream>>>(ctxb, wpb, bp, out);
}

// Round 7
// 314.842 us; speedup vs baseline: 1.0015x; 1.0015x over previous
//
#include <hip/hip_runtime.h>
#include <stdint.h>

// Problem constants (B,S,D,H fixed by the reference)
#define SEQ 1568
#define SEQV 1600   // vtb padded s-stride: 1600*2B = 25 full 128B lines
#define DIM 1024
#define NB 4
#define NH 16
#define HD 64

typedef unsigned short u16;
typedef __bf16 bf16x8 __attribute__((ext_vector_type(8)));
typedef float f32x4 __attribute__((ext_vector_type(4)));

// log2(e)/8: folded into q so QK^T scores come out in exp2 domain
#define QSCALE 0.18033688011112042f

// sP row stride (u16). MUST be >= 64 (P tile is 32 x 64); 72 = 64 + 8 pad.
#define PSTR 72

// async global->LDS, 16B per lane. LDS dest is wave-uniform base + lane*16.
__device__ __forceinline__ void load_lds16(const u16* g, u16* s) {
  __builtin_amdgcn_global_load_lds((__attribute__((address_space(1))) void*)g,
                                   (__attribute__((address_space(3))) void*)s,
                                   16, 0, 0);
}

// ---------------------------------------------------------------------------
// Fused fp32 -> bf16 convert of x + all 4 weights (one launch, 4 elems/thread)
// ---------------------------------------------------------------------------
__global__ __launch_bounds__(256) void cvt_all(
    const float* __restrict__ x,  const float* __restrict__ wq,
    const float* __restrict__ wk, const float* __restrict__ wv,
    const float* __restrict__ wp,
    u16* __restrict__ xb, u16* __restrict__ wqb, u16* __restrict__ wkb,
    u16* __restrict__ wvb, u16* __restrict__ wpb) {
  int i = blockIdx.x * 256 + threadIdx.x;   // grid sized exactly: 2654208 total
  const float* src; u16* dst; int off;
  if (i < 1605632)      { src = x;  dst = xb;  off = i; }
  else if (i < 1867776) { src = wq; dst = wqb; off = i - 1605632; }
  else if (i < 2129920) { src = wk; dst = wkb; off = i - 1867776; }
  else if (i < 2392064) { src = wv; dst = wvb; off = i - 2129920; }
  else                  { src = wp; dst = wpb; off = i - 2392064; }
  float4 v = ((const float4*)src)[off];
  union { unsigned long long u; __bf16 h[4]; } o;
  o.h[0] = (__bf16)v.x; o.h[1] = (__bf16)v.y;
  o.h[2] = (__bf16)v.z; o.h[3] = (__bf16)v.w;
  ((unsigned long long*)dst)[off] = o.u;
}

// ---------------------------------------------------------------------------
// QKV projection GEMM, BK=64, DOUBLE-BUFFERED K-loop.
// One barrier per K-iter: after the barrier publishing tile k, tile k+1's
// global_load_lds are issued into the other buffer and stay in flight across
// the whole ds_read+MFMA phase; they drain at the NEXT barrier. This is the
// prefetch-across-barrier structure the single-buffer 2-barrier loop cannot
// express (R6: MfmaUtil 16%, ~800cyc/iter vs 155cyc of MFMA).
// LDS 64KB -> 2 blocks/CU. Swizzled 128B rows: conflicts = 0 (R6 verified).
// Blocks never straddle a batch boundary; vtb rows padded to SEQV -> every
// 128B output line written by one block (no cross-XCD false sharing).
// ---------------------------------------------------------------------------
__global__ __launch_bounds__(256) void gemm_qkv(
    const u16* __restrict__ xb,
    const u16* __restrict__ wq, const u16* __restrict__ wk, const u16* __restrict__ wv,
    const float* __restrict__ bq, const float* __restrict__ bk, const float* __restrict__ bv,
    u16* __restrict__ qo, u16* __restrict__ ko, u16* __restrict__ vto) {
  const int z = blockIdx.z;
  const u16* W = (z == 0) ? wq : (z == 1) ? wk : wv;
  const float* bias = (z == 0) ? bq : (z == 1) ? bk : bv;

  __shared__ __align__(16) u16 sA[2][128 * 64];
  __shared__ __align__(16) u16 sB[2][128 * 64];

  const int tid = threadIdx.x;
  const int wave = tid >> 6;
  const int lane = tid & 63;
  const int l15 = lane & 15;
  const int quad = lane >> 4;
  const int bi = blockIdx.y / 13;        // batch
  const int st = blockIdx.y % 13;        // s-tile within batch (tile 12: 32 rows)
  const int bn = blockIdx.x * 128;
  const int wm = (wave >> 1) * 64;
  const int wn = (wave & 1) * 64;

  const int jrow = lane >> 3;            // 0..7
  const int cg = (lane & 7) ^ jrow;      // xor-swizzled chunk to fetch
  const int j7 = l15 & 7;
  const int r0 = wave * 32;              // this wave's staging rows

#define QKV_STAGE(cb, K0)                                                     \
  do {                                                                        \
    _Pragma("unroll") for (int i_ = 0; i_ < 4; i_++) {                        \
      int srow_ = st * 128 + r0 + i_ * 8 + jrow;                              \
      if (srow_ >= SEQ) srow_ = SEQ - 1;                                      \
      load_lds16(xb + (size_t)(bi * SEQ + srow_) * DIM + (K0) + cg * 8,       \
                 &sA[cb][(r0 + i_ * 8) * 64]);                                \
    }                                                                         \
    _Pragma("unroll") for (int i_ = 0; i_ < 4; i_++)                          \
      load_lds16(W + (size_t)(bn + r0 + i_ * 8 + jrow) * DIM + (K0) + cg * 8, \
                 &sB[cb][(r0 + i_ * 8) * 64]);                                \
  } while (0)

  f32x4 acc[4][4] = {};

  QKV_STAGE(0, 0);
  int cur = 0;
  for (int it = 0; it < 16; it++) {
    __syncthreads();   // drains this wave's outstanding loads (tile `it`),
                       // and ensures everyone is done reading buf cur^1
    if (it < 15) QKV_STAGE(cur ^ 1, (it + 1) * 64);  // in flight during MFMA

    const u16* A = &sA[cur][0];
    const u16* Bt = &sB[cur][0];
    bf16x8 a[2][4], b[2][4];
#pragma unroll
    for (int kk = 0; kk < 2; kk++) {
#pragma unroll
      for (int mt = 0; mt < 4; mt++)
        a[kk][mt] = *(const bf16x8*)&A[(wm + mt * 16 + l15) * 64 +
                                       (((kk * 4 + quad) ^ j7) * 8)];
#pragma unroll
      for (int nt = 0; nt < 4; nt++)
        b[kk][nt] = *(const bf16x8*)&Bt[(wn + nt * 16 + l15) * 64 +
                                        (((kk * 4 + quad) ^ j7) * 8)];
    }
#pragma unroll
    for (int kk = 0; kk < 2; kk++)
#pragma unroll
      for (int mt = 0; mt < 4; mt++)
#pragma unroll
        for (int nt = 0; nt < 4; nt++)
          acc[mt][nt] = __builtin_amdgcn_mfma_f32_16x16x32_bf16(
              a[kk][mt], b[kk][nt], acc[mt][nt], 0, 0, 0);
    cur ^= 1;
  }
#undef QKV_STAGE

  // epilogue: C/D layout col=lane&15, row=quad*4+reg
#pragma unroll
  for (int nt = 0; nt < 4; nt++) {
    const int n = bn + wn + nt * 16 + l15;
    const float bia = bias[n];
    const int h = n >> 6, d = n & 63;
#pragma unroll
    for (int mt = 0; mt < 4; mt++) {
      const int sbase = st * 128 + wm + mt * 16 + quad * 4;
#pragma unroll
      for (int r = 0; r < 4; r++) {
        const int s = sbase + r;
        if (s < SEQ) {
          float val = acc[mt][nt][r] + bia;
          if (z == 0) val *= QSCALE;
          const __bf16 o = (__bf16)val;
          if (z == 0)
            *(__bf16*)&qo[(((size_t)(bi * NH + h)) * SEQ + s) * HD + d] = o;
          else if (z == 1)
            *(__bf16*)&ko[(((size_t)(bi * NH + h)) * SEQ + s) * HD + d] = o;
          else
            *(__bf16*)&vto[(((size_t)(bi * NH + h)) * HD + d) * SEQV + s] = o;
        }
      }
    }
  }
}

// ---------------------------------------------------------------------------
// Flash attention (unchanged): no-max exp2-domain softmax,
// 4 waves x 32 q-rows, j-tiles of 64, 24 clean tiles + explicit 32-j tail.
// ---------------------------------------------------------------------------
__global__ __launch_bounds__(256, 4) void attn(
    const u16* __restrict__ q, const u16* __restrict__ k,
    const u16* __restrict__ vt, u16* __restrict__ ctx) {
  const int bh = blockIdx.y;   // 0..63 (b*16+h)
  const int qt = blockIdx.x;   // 0..12, 128 q-rows each
  const int tid = threadIdx.x;
  const int wave = tid >> 6, lane = tid & 63, l15 = lane & 15, quad = lane >> 4;

  __shared__ __align__(16) u16 sK[64 * 64];        // [j][d], chunk-swizzled
  __shared__ __align__(16) u16 sV[64 * 64];        // [d][j], chunk-swizzled
  __shared__ __align__(16) u16 sP[4][32 * PSTR];   // per-wave P [i][j]

  const u16* qh = q + (size_t)bh * (SEQ * HD);
  const u16* kh = k + (size_t)bh * (SEQ * HD);
  const u16* vh = vt + (size_t)bh * (HD * SEQV);

  bf16x8 aq[2][2];
#pragma unroll
  for (int mt = 0; mt < 2; mt++) {
    int qrow = qt * 128 + wave * 32 + mt * 16 + l15;
    int qr = qrow < SEQ ? qrow : SEQ - 1;
    aq[mt][0] = *(const bf16x8*)&qh[(size_t)qr * HD + quad * 8];
    aq[mt][1] = *(const bf16x8*)&qh[(size_t)qr * HD + 32 + quad * 8];
  }

  f32x4 o[2][4] = {};
  float lrow[2][4] = {};

  const int jrow = lane >> 3;
  const int cg = (lane & 7) ^ jrow;
  u16* sPw = sP[wave];
  const int j7 = l15 & 7;

  // ---- 24 full 64-j tiles ----
  for (int j0 = 0; j0 < 1536; j0 += 64) {
    __syncthreads();
    load_lds16(&kh[(size_t)(j0 + wave * 16 + jrow) * HD + cg * 8], &sK[(wave * 16) * 64]);
    load_lds16(&kh[(size_t)(j0 + wave * 16 + 8 + jrow) * HD + cg * 8], &sK[(wave * 16 + 8) * 64]);
    load_lds16(&vh[(size_t)(wave * 16 + jrow) * SEQV + j0 + cg * 8], &sV[(wave * 16) * 64]);
    load_lds16(&vh[(size_t)(wave * 16 + 8 + jrow) * SEQV + j0 + cg * 8], &sV[(wave * 16 + 8) * 64]);
    __syncthreads();

#pragma unroll
    for (int mt = 0; mt < 2; mt++) {
      f32x4 s[4];
#pragma unroll
      for (int jt = 0; jt < 4; jt++) {
        const int j = jt * 16 + l15;
        bf16x8 b0 = *(const bf16x8*)&sK[j * 64 + ((quad ^ j7) * 8)];
        bf16x8 b1 = *(const bf16x8*)&sK[j * 64 + (((4 + quad) ^ j7) * 8)];
        f32x4 acc = {};
        acc = __builtin_amdgcn_mfma_f32_16x16x32_bf16(aq[mt][0], b0, acc, 0, 0, 0);
        acc = __builtin_amdgcn_mfma_f32_16x16x32_bf16(aq[mt][1], b1, acc, 0, 0, 0);
        s[jt] = acc;
      }
#pragma unroll
      for (int jt = 0; jt < 4; jt++)
#pragma unroll
        for (int r = 0; r < 4; r++) {
          float p = __builtin_exp2f(s[jt][r]);
          lrow[mt][r] += p;
          *(__bf16*)&sPw[(mt * 16 + quad * 4 + r) * PSTR + jt * 16 + l15] = (__bf16)p;
        }
    }

    asm volatile("s_waitcnt lgkmcnt(0)" ::: "memory");

#pragma unroll
    for (int kc = 0; kc < 2; kc++) {
      bf16x8 ap0 = *(const bf16x8*)&sPw[l15 * PSTR + kc * 32 + quad * 8];
      bf16x8 ap1 = *(const bf16x8*)&sPw[(16 + l15) * PSTR + kc * 32 + quad * 8];
#pragma unroll
      for (int dt = 0; dt < 4; dt++) {
        const int d7 = l15 & 7;
        bf16x8 bv = *(const bf16x8*)&sV[(dt * 16 + l15) * 64 + (((kc * 4 + quad) ^ d7) * 8)];
        o[0][dt] = __builtin_amdgcn_mfma_f32_16x16x32_bf16(ap0, bv, o[0][dt], 0, 0, 0);
        o[1][dt] = __builtin_amdgcn_mfma_f32_16x16x32_bf16(ap1, bv, o[1][dt], 0, 0, 0);
      }
    }
  }

  // ---- tail tile: j0 = 1536, 32 valid j (jt 0..1, kc 0) ----
  {
    const int j0 = 1536;
    __syncthreads();
    if (wave < 2) {
      load_lds16(&kh[(size_t)(j0 + wave * 16 + jrow) * HD + cg * 8], &sK[(wave * 16) * 64]);
      load_lds16(&kh[(size_t)(j0 + wave * 16 + 8 + jrow) * HD + cg * 8], &sK[(wave * 16 + 8) * 64]);
    }
    load_lds16(&vh[(size_t)(wave * 16 + jrow) * SEQV + j0 + cg * 8], &sV[(wave * 16) * 64]);
    load_lds16(&vh[(size_t)(wave * 16 + 8 + jrow) * SEQV + j0 + cg * 8], &sV[(wave * 16 + 8) * 64]);
    __syncthreads();

#pragma unroll
    for (int mt = 0; mt < 2; mt++) {
      f32x4 s[2];
#pragma unroll
      for (int jt = 0; jt < 2; jt++) {
        const int j = jt * 16 + l15;
        bf16x8 b0 = *(const bf16x8*)&sK[j * 64 + ((quad ^ j7) * 8)];
        bf16x8 b1 = *(const bf16x8*)&sK[j * 64 + (((4 + quad) ^ j7) * 8)];
        f32x4 acc = {};
        acc = __builtin_amdgcn_mfma_f32_16x16x32_bf16(aq[mt][0], b0, acc, 0, 0, 0);
        acc = __builtin_amdgcn_mfma_f32_16x16x32_bf16(aq[mt][1], b1, acc, 0, 0, 0);
        s[jt] = acc;
      }
#pragma unroll
      for (int jt = 0; jt < 2; jt++)
#pragma unroll
        for (int r = 0; r < 4; r++) {
          float p = __builtin_exp2f(s[jt][r]);
          lrow[mt][r] += p;
          *(__bf16*)&sPw[(mt * 16 + quad * 4 + r) * PSTR + jt * 16 + l15] = (__bf16)p;
        }
    }

    asm volatile("s_waitcnt lgkmcnt(0)" ::: "memory");

    {
      bf16x8 ap0 = *(const bf16x8*)&sPw[l15 * PSTR + quad * 8];
      bf16x8 ap1 = *(const bf16x8*)&sPw[(16 + l15) * PSTR + quad * 8];
#pragma unroll
      for (int dt = 0; dt < 4; dt++) {
        const int d7 = l15 & 7;
        bf16x8 bv = *(const bf16x8*)&sV[(dt * 16 + l15) * 64 + ((quad ^ d7) * 8)];
        o[0][dt] = __builtin_amdgcn_mfma_f32_16x16x32_bf16(ap0, bv, o[0][dt], 0, 0, 0);
        o[1][dt] = __builtin_amdgcn_mfma_f32_16x16x32_bf16(ap1, bv, o[1][dt], 0, 0, 0);
      }
    }
  }

  // epilogue
  const int bi = bh >> 4, h = bh & 15;
#pragma unroll
  for (int mt = 0; mt < 2; mt++) {
#pragma unroll
    for (int r = 0; r < 4; r++) {
      float l = lrow[mt][r];
#pragma unroll
      for (int off = 8; off >= 1; off >>= 1) l += __shfl_xor(l, off, 16);
      const int srow = qt * 128 + wave * 32 + mt * 16 + quad * 4 + r;
      if (srow < SEQ) {
        const float inv = 1.0f / l;
#pragma unroll
        for (int dt = 0; dt < 4; dt++)
          *(__bf16*)&ctx[((size_t)(bi * SEQ + srow)) * DIM + h * HD + dt * 16 + l15] =
              (__bf16)(o[mt][dt][r] * inv);
      }
    }
  }
}

// ---------------------------------------------------------------------------
// Output projection (R5 version — 128x128 BK32; the R6 64x128 split regressed
// ~30us from doubled Wp re-reads): out = ctx @ Wp^T + bp, fp32 out.
// ---------------------------------------------------------------------------
__global__ __launch_bounds__(256) void gemm_out(
    const u16* __restrict__ ctx, const u16* __restrict__ wp,
    const float* __restrict__ bp, float* __restrict__ out) {
  __shared__ __align__(16) u16 sA[128 * 32];
  __shared__ __align__(16) u16 sB[128 * 32];

  const int tid = threadIdx.x;
  const int wave = tid >> 6;
  const int lane = tid & 63;
  const int l15 = lane & 15;
  const int quad = lane >> 4;
  const int bm = blockIdx.y * 128;
  const int bn = blockIdx.x * 128;
  const int wm = (wave >> 1) * 64;
  const int wn = (wave & 1) * 64;
  const int sr = lane >> 2;
  const int sc = (lane & 3) * 8;
  const int r0 = wave * 32;

  f32x4 acc[4][4] = {};

  for (int k0 = 0; k0 < DIM; k0 += 32) {
    __syncthreads();
    {
      const u16* gA = ctx + (size_t)(bm + r0 + sr) * DIM + k0 + sc;
      load_lds16(gA, &sA[r0 * 32]);
      load_lds16(gA + 16 * DIM, &sA[(r0 + 16) * 32]);
      const u16* gB = wp + (size_t)(bn + r0 + sr) * DIM + k0 + sc;
      load_lds16(gB, &sB[r0 * 32]);
      load_lds16(gB + 16 * DIM, &sB[(r0 + 16) * 32]);
    }
    __syncthreads();

    bf16x8 a[4], b[4];
#pragma unroll
    for (int mt = 0; mt < 4; mt++)
      a[mt] = *(const bf16x8*)&sA[(wm + mt * 16 + l15) * 32 + quad * 8];
#pragma unroll
    for (int nt = 0; nt < 4; nt++)
      b[nt] = *(const bf16x8*)&sB[(wn + nt * 16 + l15) * 32 + quad * 8];
#pragma unroll
    for (int mt = 0; mt < 4; mt++)
#pragma unroll
      for (int nt = 0; nt < 4; nt++)
        acc[mt][nt] = __builtin_amdgcn_mfma_f32_16x16x32_bf16(a[mt], b[nt], acc[mt][nt], 0, 0, 0);
  }

#pragma unroll
  for (int nt = 0; nt < 4; nt++) {
    const int n = bn + wn + nt * 16 + l15;
    const float bia = bp[n];
#pragma unroll
    for (int mt = 0; mt < 4; mt++) {
      const int mbase = bm + wm + mt * 16 + quad * 4;
#pragma unroll
      for (int r = 0; r < 4; r++)
        out[(size_t)(mbase + r) * DIM + n] = acc[mt][nt][r] + bia;
    }
  }
}

// ---------------------------------------------------------------------------
// Workspace layout (bytes):
//  xb   @ 0         : 12,845,056  (x bf16)
//  wqb  @ 12845056  :  2,097,152
//  wkb  @ 14942208  :  2,097,152
//  wvb  @ 17039360  :  2,097,152
//  wpb  @ 19136512  :  2,097,152
//  qb   @ 21233664  : 12,845,056  ([B,H,S,HD] bf16, pre-scaled by QSCALE)
//  kb   @ 34078720  : 12,845,056  ([B,H,S,HD] bf16)
//  vtb  @ 46923776  : 13,107,200  ([B,H,HD,SEQV=1600] bf16, line-aligned rows)
//  ctxb @ 60030976  : 12,845,056  ([B,S,D] bf16)
//  total 72,876,032 bytes
// ---------------------------------------------------------------------------
extern "C" void kernel_launch(void* const* d_in, const int* in_sizes, int n_in,
                              void* d_out, int out_size, void* d_ws, size_t ws_size,
                              hipStream_t stream) {
  const float* x  = (const float*)d_in[0];
  const float* Wq = (const float*)d_in[1];
  const float* bq = (const float*)d_in[2];
  const float* Wk = (const float*)d_in[3];
  const float* bk = (const float*)d_in[4];
  const float* Wv = (const float*)d_in[5];
  const float* bv = (const float*)d_in[6];
  const float* Wp = (const float*)d_in[7];
  const float* bp = (const float*)d_in[8];
  float* out = (float*)d_out;

  char* ws = (char*)d_ws;
  u16* xb   = (u16*)(ws + 0);
  u16* wqb  = (u16*)(ws + 12845056);
  u16* wkb  = (u16*)(ws + 14942208);
  u16* wvb  = (u16*)(ws + 17039360);
  u16* wpb  = (u16*)(ws + 19136512);
  u16* qb   = (u16*)(ws + 21233664);
  u16* kb   = (u16*)(ws + 34078720);
  u16* vtb  = (u16*)(ws + 46923776);
  u16* ctxb = (u16*)(ws + 60030976);

  cvt_all<<<10368, 256, 0, stream>>>(x, Wq, Wk, Wv, Wp, xb, wqb, wkb, wvb, wpb);
  gemm_qkv<<<dim3(8, 52, 3), 256, 0, stream>>>(xb, wqb, wkb, wvb, bq, bk, bv, qb, kb, vtb);
  attn<<<dim3(13, 64), 256, 0, stream>>>(qb, kb, vtb, ctxb);
  gemm_out<<<dim3(8, 49), 256, 0, stream>>>(ctxb, wpb, bp, out);
}

// Round 8
// 304.789 us; speedup vs baseline: 1.0346x; 1.0330x over previous
//
#include <hip/hip_runtime.h>
#include <stdint.h>

// Problem constants (B,S,D,H fixed by the reference)
#define SEQ 1568
#define SEQV 1600   // vtb padded s-stride: 1600*2B = 25 full 128B lines
#define DIM 1024
#define NB 4
#define NH 16
#define HD 64

typedef unsigned short u16;
typedef __bf16 bf16x8 __attribute__((ext_vector_type(8)));
typedef float f32x4 __attribute__((ext_vector_type(4)));

// log2(e)/8: folded into q so QK^T scores come out in exp2 domain
#define QSCALE 0.18033688011112042f

// sP row stride (u16). MUST be >= 64 (P tile is 32 x 64); 72 = 64 + 8 pad.
#define PSTR 72

// async global->LDS, 16B per lane. LDS dest is wave-uniform base + lane*16.
__device__ __forceinline__ void load_lds16(const u16* g, u16* s) {
  __builtin_amdgcn_global_load_lds((__attribute__((address_space(1))) void*)g,
                                   (__attribute__((address_space(3))) void*)s,
                                   16, 0, 0);
}

// ---------------------------------------------------------------------------
// Fused fp32 -> bf16 convert of x + all 4 weights (one launch, 4 elems/thread)
// ---------------------------------------------------------------------------
__global__ __launch_bounds__(256) void cvt_all(
    const float* __restrict__ x,  const float* __restrict__ wq,
    const float* __restrict__ wk, const float* __restrict__ wv,
    const float* __restrict__ wp,
    u16* __restrict__ xb, u16* __restrict__ wqb, u16* __restrict__ wkb,
    u16* __restrict__ wvb, u16* __restrict__ wpb) {
  int i = blockIdx.x * 256 + threadIdx.x;   // grid sized exactly: 2654208 total
  const float* src; u16* dst; int off;
  if (i < 1605632)      { src = x;  dst = xb;  off = i; }
  else if (i < 1867776) { src = wq; dst = wqb; off = i - 1605632; }
  else if (i < 2129920) { src = wk; dst = wkb; off = i - 1867776; }
  else if (i < 2392064) { src = wv; dst = wvb; off = i - 2129920; }
  else                  { src = wp; dst = wpb; off = i - 2392064; }
  float4 v = ((const float4*)src)[off];
  union { unsigned long long u; __bf16 h[4]; } o;
  o.h[0] = (__bf16)v.x; o.h[1] = (__bf16)v.y;
  o.h[2] = (__bf16)v.z; o.h[3] = (__bf16)v.w;
  ((unsigned long long*)dst)[off] = o.u;
}

// ---------------------------------------------------------------------------
// QKV projection GEMM — exact R6 kernel (best measured: 104us, conflicts 0).
// BK=64 single-buffer, 16 K-iters, 32 MFMA per drain. XOR chunk swizzle:
// phys slot p of row r holds logical chunk p^(r&7) -> b128 reads conflict-
// free. R7's explicit double-buffer REGRESSED (114us): __syncthreads still
// drains vmcnt(0), and 64KB LDS halved residency — per m99/m131-141, source-
// level pipelining can't beat this structure. Do not re-attempt.
// Blocks never straddle a batch boundary; vtb rows padded to SEQV -> every
// 128B output line written by one block (no cross-XCD false sharing).
// ---------------------------------------------------------------------------
__global__ __launch_bounds__(256) void gemm_qkv(
    const u16* __restrict__ xb,
    const u16* __restrict__ wq, const u16* __restrict__ wk, const u16* __restrict__ wv,
    const float* __restrict__ bq, const float* __restrict__ bk, const float* __restrict__ bv,
    u16* __restrict__ qo, u16* __restrict__ ko, u16* __restrict__ vto) {
  const int z = blockIdx.z;
  const u16* W = (z == 0) ? wq : (z == 1) ? wk : wv;
  const float* bias = (z == 0) ? bq : (z == 1) ? bk : bv;

  __shared__ __align__(16) u16 sA[128 * 64];
  __shared__ __align__(16) u16 sB[128 * 64];

  const int tid = threadIdx.x;
  const int wave = tid >> 6;
  const int lane = tid & 63;
  const int l15 = lane & 15;
  const int quad = lane >> 4;
  const int bi = blockIdx.y / 13;        // batch
  const int st = blockIdx.y % 13;        // s-tile within batch (tile 12: 32 rows)
  const int bn = blockIdx.x * 128;
  const int wm = (wave >> 1) * 64;
  const int wn = (wave & 1) * 64;

  const int jrow = lane >> 3;            // 0..7
  const int cg = (lane & 7) ^ jrow;      // xor-swizzled chunk to fetch
  const int j7 = l15 & 7;
  const int r0 = wave * 32;              // this wave's staging rows

  f32x4 acc[4][4] = {};

  for (int k0 = 0; k0 < DIM; k0 += 64) {
    __syncthreads();
#pragma unroll
    for (int i = 0; i < 4; i++) {
      int srow = st * 128 + r0 + i * 8 + jrow;
      if (srow >= SEQ) srow = SEQ - 1;   // clamp for the partial tail tile
      load_lds16(xb + (size_t)(bi * SEQ + srow) * DIM + k0 + cg * 8,
                 &sA[(r0 + i * 8) * 64]);
    }
#pragma unroll
    for (int i = 0; i < 4; i++)
      load_lds16(W + (size_t)(bn + r0 + i * 8 + jrow) * DIM + k0 + cg * 8,
                 &sB[(r0 + i * 8) * 64]);
    __syncthreads();

    bf16x8 a[2][4], b[2][4];
#pragma unroll
    for (int kk = 0; kk < 2; kk++) {
#pragma unroll
      for (int mt = 0; mt < 4; mt++)
        a[kk][mt] = *(const bf16x8*)&sA[(wm + mt * 16 + l15) * 64 +
                                        (((kk * 4 + quad) ^ j7) * 8)];
#pragma unroll
      for (int nt = 0; nt < 4; nt++)
        b[kk][nt] = *(const bf16x8*)&sB[(wn + nt * 16 + l15) * 64 +
                                        (((kk * 4 + quad) ^ j7) * 8)];
    }
#pragma unroll
    for (int kk = 0; kk < 2; kk++)
#pragma unroll
      for (int mt = 0; mt < 4; mt++)
#pragma unroll
        for (int nt = 0; nt < 4; nt++)
          acc[mt][nt] = __builtin_amdgcn_mfma_f32_16x16x32_bf16(
              a[kk][mt], b[kk][nt], acc[mt][nt], 0, 0, 0);
  }

  // epilogue: C/D layout col=lane&15, row=quad*4+reg
#pragma unroll
  for (int nt = 0; nt < 4; nt++) {
    const int n = bn + wn + nt * 16 + l15;
    const float bia = bias[n];
    const int h = n >> 6, d = n & 63;
#pragma unroll
    for (int mt = 0; mt < 4; mt++) {
      const int sbase = st * 128 + wm + mt * 16 + quad * 4;
#pragma unroll
      for (int r = 0; r < 4; r++) {
        const int s = sbase + r;
        if (s < SEQ) {
          float val = acc[mt][nt][r] + bia;
          if (z == 0) val *= QSCALE;
          const __bf16 o = (__bf16)val;
          if (z == 0)
            *(__bf16*)&qo[(((size_t)(bi * NH + h)) * SEQ + s) * HD + d] = o;
          else if (z == 1)
            *(__bf16*)&ko[(((size_t)(bi * NH + h)) * SEQ + s) * HD + d] = o;
          else
            *(__bf16*)&vto[(((size_t)(bi * NH + h)) * HD + d) * SEQV + s] = o;
        }
      }
    }
  }
}

// ---------------------------------------------------------------------------
// Flash attention (unchanged): no-max exp2-domain softmax,
// 4 waves x 32 q-rows, j-tiles of 64, 24 clean tiles + explicit 32-j tail.
// ---------------------------------------------------------------------------
__global__ __launch_bounds__(256, 4) void attn(
    const u16* __restrict__ q, const u16* __restrict__ k,
    const u16* __restrict__ vt, u16* __restrict__ ctx) {
  const int bh = blockIdx.y;   // 0..63 (b*16+h)
  const int qt = blockIdx.x;   // 0..12, 128 q-rows each
  const int tid = threadIdx.x;
  const int wave = tid >> 6, lane = tid & 63, l15 = lane & 15, quad = lane >> 4;

  __shared__ __align__(16) u16 sK[64 * 64];        // [j][d], chunk-swizzled
  __shared__ __align__(16) u16 sV[64 * 64];        // [d][j], chunk-swizzled
  __shared__ __align__(16) u16 sP[4][32 * PSTR];   // per-wave P [i][j]

  const u16* qh = q + (size_t)bh * (SEQ * HD);
  const u16* kh = k + (size_t)bh * (SEQ * HD);
  const u16* vh = vt + (size_t)bh * (HD * SEQV);

  bf16x8 aq[2][2];
#pragma unroll
  for (int mt = 0; mt < 2; mt++) {
    int qrow = qt * 128 + wave * 32 + mt * 16 + l15;
    int qr = qrow < SEQ ? qrow : SEQ - 1;
    aq[mt][0] = *(const bf16x8*)&qh[(size_t)qr * HD + quad * 8];
    aq[mt][1] = *(const bf16x8*)&qh[(size_t)qr * HD + 32 + quad * 8];
  }

  f32x4 o[2][4] = {};
  float lrow[2][4] = {};

  const int jrow = lane >> 3;
  const int cg = (lane & 7) ^ jrow;
  u16* sPw = sP[wave];
  const int j7 = l15 & 7;

  // ---- 24 full 64-j tiles ----
  for (int j0 = 0; j0 < 1536; j0 += 64) {
    __syncthreads();
    load_lds16(&kh[(size_t)(j0 + wave * 16 + jrow) * HD + cg * 8], &sK[(wave * 16) * 64]);
    load_lds16(&kh[(size_t)(j0 + wave * 16 + 8 + jrow) * HD + cg * 8], &sK[(wave * 16 + 8) * 64]);
    load_lds16(&vh[(size_t)(wave * 16 + jrow) * SEQV + j0 + cg * 8], &sV[(wave * 16) * 64]);
    load_lds16(&vh[(size_t)(wave * 16 + 8 + jrow) * SEQV + j0 + cg * 8], &sV[(wave * 16 + 8) * 64]);
    __syncthreads();

#pragma unroll
    for (int mt = 0; mt < 2; mt++) {
      f32x4 s[4];
#pragma unroll
      for (int jt = 0; jt < 4; jt++) {
        const int j = jt * 16 + l15;
        bf16x8 b0 = *(const bf16x8*)&sK[j * 64 + ((quad ^ j7) * 8)];
        bf16x8 b1 = *(const bf16x8*)&sK[j * 64 + (((4 + quad) ^ j7) * 8)];
        f32x4 acc = {};
        acc = __builtin_amdgcn_mfma_f32_16x16x32_bf16(aq[mt][0], b0, acc, 0, 0, 0);
        acc = __builtin_amdgcn_mfma_f32_16x16x32_bf16(aq[mt][1], b1, acc, 0, 0, 0);
        s[jt] = acc;
      }
#pragma unroll
      for (int jt = 0; jt < 4; jt++)
#pragma unroll
        for (int r = 0; r < 4; r++) {
          float p = __builtin_exp2f(s[jt][r]);
          lrow[mt][r] += p;
          *(__bf16*)&sPw[(mt * 16 + quad * 4 + r) * PSTR + jt * 16 + l15] = (__bf16)p;
        }
    }

    asm volatile("s_waitcnt lgkmcnt(0)" ::: "memory");

#pragma unroll
    for (int kc = 0; kc < 2; kc++) {
      bf16x8 ap0 = *(const bf16x8*)&sPw[l15 * PSTR + kc * 32 + quad * 8];
      bf16x8 ap1 = *(const bf16x8*)&sPw[(16 + l15) * PSTR + kc * 32 + quad * 8];
#pragma unroll
      for (int dt = 0; dt < 4; dt++) {
        const int d7 = l15 & 7;
        bf16x8 bv = *(const bf16x8*)&sV[(dt * 16 + l15) * 64 + (((kc * 4 + quad) ^ d7) * 8)];
        o[0][dt] = __builtin_amdgcn_mfma_f32_16x16x32_bf16(ap0, bv, o[0][dt], 0, 0, 0);
        o[1][dt] = __builtin_amdgcn_mfma_f32_16x16x32_bf16(ap1, bv, o[1][dt], 0, 0, 0);
      }
    }
  }

  // ---- tail tile: j0 = 1536, 32 valid j (jt 0..1, kc 0) ----
  {
    const int j0 = 1536;
    __syncthreads();
    if (wave < 2) {
      load_lds16(&kh[(size_t)(j0 + wave * 16 + jrow) * HD + cg * 8], &sK[(wave * 16) * 64]);
      load_lds16(&kh[(size_t)(j0 + wave * 16 + 8 + jrow) * HD + cg * 8], &sK[(wave * 16 + 8) * 64]);
    }
    load_lds16(&vh[(size_t)(wave * 16 + jrow) * SEQV + j0 + cg * 8], &sV[(wave * 16) * 64]);
    load_lds16(&vh[(size_t)(wave * 16 + 8 + jrow) * SEQV + j0 + cg * 8], &sV[(wave * 16 + 8) * 64]);
    __syncthreads();

#pragma unroll
    for (int mt = 0; mt < 2; mt++) {
      f32x4 s[2];
#pragma unroll
      for (int jt = 0; jt < 2; jt++) {
        const int j = jt * 16 + l15;
        bf16x8 b0 = *(const bf16x8*)&sK[j * 64 + ((quad ^ j7) * 8)];
        bf16x8 b1 = *(const bf16x8*)&sK[j * 64 + (((4 + quad) ^ j7) * 8)];
        f32x4 acc = {};
        acc = __builtin_amdgcn_mfma_f32_16x16x32_bf16(aq[mt][0], b0, acc, 0, 0, 0);
        acc = __builtin_amdgcn_mfma_f32_16x16x32_bf16(aq[mt][1], b1, acc, 0, 0, 0);
        s[jt] = acc;
      }
#pragma unroll
      for (int jt = 0; jt < 2; jt++)
#pragma unroll
        for (int r = 0; r < 4; r++) {
          float p = __builtin_exp2f(s[jt][r]);
          lrow[mt][r] += p;
          *(__bf16*)&sPw[(mt * 16 + quad * 4 + r) * PSTR + jt * 16 + l15] = (__bf16)p;
        }
    }

    asm volatile("s_waitcnt lgkmcnt(0)" ::: "memory");

    {
      bf16x8 ap0 = *(const bf16x8*)&sPw[l15 * PSTR + quad * 8];
      bf16x8 ap1 = *(const bf16x8*)&sPw[(16 + l15) * PSTR + quad * 8];
#pragma unroll
      for (int dt = 0; dt < 4; dt++) {
        const int d7 = l15 & 7;
        bf16x8 bv = *(const bf16x8*)&sV[(dt * 16 + l15) * 64 + ((quad ^ d7) * 8)];
        o[0][dt] = __builtin_amdgcn_mfma_f32_16x16x32_bf16(ap0, bv, o[0][dt], 0, 0, 0);
        o[1][dt] = __builtin_amdgcn_mfma_f32_16x16x32_bf16(ap1, bv, o[1][dt], 0, 0, 0);
      }
    }
  }

  // epilogue
  const int bi = bh >> 4, h = bh & 15;
#pragma unroll
  for (int mt = 0; mt < 2; mt++) {
#pragma unroll
    for (int r = 0; r < 4; r++) {
      float l = lrow[mt][r];
#pragma unroll
      for (int off = 8; off >= 1; off >>= 1) l += __shfl_xor(l, off, 16);
      const int srow = qt * 128 + wave * 32 + mt * 16 + quad * 4 + r;
      if (srow < SEQ) {
        const float inv = 1.0f / l;
#pragma unroll
        for (int dt = 0; dt < 4; dt++)
          *(__bf16*)&ctx[((size_t)(bi * SEQ + srow)) * DIM + h * HD + dt * 16 + l15] =
              (__bf16)(o[mt][dt][r] * inv);
      }
    }
  }
}

// ---------------------------------------------------------------------------
// Output projection, BK=64 single-buffer with XOR swizzle (the R6 qkv
// transform that gave 119->104 and conflicts->0), 128x128 tile, grid (8,49).
// 6272 = 49*128 exactly: no row masks. fp32 out.
// ---------------------------------------------------------------------------
__global__ __launch_bounds__(256) void gemm_out(
    const u16* __restrict__ ctx, const u16* __restrict__ wp,
    const float* __restrict__ bp, float* __restrict__ out) {
  __shared__ __align__(16) u16 sA[128 * 64];
  __shared__ __align__(16) u16 sB[128 * 64];

  const int tid = threadIdx.x;
  const int wave = tid >> 6;
  const int lane = tid & 63;
  const int l15 = lane & 15;
  const int quad = lane >> 4;
  const int bm = blockIdx.y * 128;
  const int bn = blockIdx.x * 128;
  const int wm = (wave >> 1) * 64;
  const int wn = (wave & 1) * 64;

  const int jrow = lane >> 3;
  const int cg = (lane & 7) ^ jrow;
  const int j7 = l15 & 7;
  const int r0 = wave * 32;

  f32x4 acc[4][4] = {};

  for (int k0 = 0; k0 < DIM; k0 += 64) {
    __syncthreads();
#pragma unroll
    for (int i = 0; i < 4; i++)
      load_lds16(ctx + (size_t)(bm + r0 + i * 8 + jrow) * DIM + k0 + cg * 8,
                 &sA[(r0 + i * 8) * 64]);
#pragma unroll
    for (int i = 0; i < 4; i++)
      load_lds16(wp + (size_t)(bn + r0 + i * 8 + jrow) * DIM + k0 + cg * 8,
                 &sB[(r0 + i * 8) * 64]);
    __syncthreads();

    bf16x8 a[2][4], b[2][4];
#pragma unroll
    for (int kk = 0; kk < 2; kk++) {
#pragma unroll
      for (int mt = 0; mt < 4; mt++)
        a[kk][mt] = *(const bf16x8*)&sA[(wm + mt * 16 + l15) * 64 +
                                        (((kk * 4 + quad) ^ j7) * 8)];
#pragma unroll
      for (int nt = 0; nt < 4; nt++)
        b[kk][nt] = *(const bf16x8*)&sB[(wn + nt * 16 + l15) * 64 +
                                        (((kk * 4 + quad) ^ j7) * 8)];
    }
#pragma unroll
    for (int kk = 0; kk < 2; kk++)
#pragma unroll
      for (int mt = 0; mt < 4; mt++)
#pragma unroll
        for (int nt = 0; nt < 4; nt++)
          acc[mt][nt] = __builtin_amdgcn_mfma_f32_16x16x32_bf16(
              a[kk][mt], b[kk][nt], acc[mt][nt], 0, 0, 0);
  }

#pragma unroll
  for (int nt = 0; nt < 4; nt++) {
    const int n = bn + wn + nt * 16 + l15;
    const float bia = bp[n];
#pragma unroll
    for (int mt = 0; mt < 4; mt++) {
      const int mbase = bm + wm + mt * 16 + quad * 4;
#pragma unroll
      for (int r = 0; r < 4; r++)
        out[(size_t)(mbase + r) * DIM + n] = acc[mt][nt][r] + bia;
    }
  }
}

// ---------------------------------------------------------------------------
// Workspace layout (bytes):
//  xb   @ 0         : 12,845,056  (x bf16)
//  wqb  @ 12845056  :  2,097,152
//  wkb  @ 14942208  :  2,097,152
//  wvb  @ 17039360  :  2,097,152
//  wpb  @ 19136512  :  2,097,152
//  qb   @ 21233664  : 12,845,056  ([B,H,S,HD] bf16, pre-scaled by QSCALE)
//  kb   @ 34078720  : 12,845,056  ([B,H,S,HD] bf16)
//  vtb  @ 46923776  : 13,107,200  ([B,H,HD,SEQV=1600] bf16, line-aligned rows)
//  ctxb @ 60030976  : 12,845,056  ([B,S,D] bf16)
//  total 72,876,032 bytes
// ---------------------------------------------------------------------------
extern "C" void kernel_launch(void* const* d_in, const int* in_sizes, int n_in,
                              void* d_out, int out_size, void* d_ws, size_t ws_size,
                              hipStream_t stream) {
  const float* x  = (const float*)d_in[0];
  const float* Wq = (const float*)d_in[1];
  const float* bq = (const float*)d_in[2];
  const float* Wk = (const float*)d_in[3];
  const float* bk = (const float*)d_in[4];
  const float* Wv = (const float*)d_in[5];
  const float* bv = (const float*)d_in[6];
  const float* Wp = (const float*)d_in[7];
  const float* bp = (const float*)d_in[8];
  float* out = (float*)d_out;

  char* ws = (char*)d_ws;
  u16* xb   = (u16*)(ws + 0);
  u16* wqb  = (u16*)(ws + 12845056);
  u16* wkb  = (u16*)(ws + 14942208);
  u16* wvb  = (u16*)(ws + 17039360);
  u16* wpb  = (u16*)(ws + 19136512);
  u16* qb   = (u16*)(ws + 21233664);
  u16* kb   = (u16*)(ws + 34078720);
  u16* vtb  = (u16*)(ws + 46923776);
  u16* ctxb = (u16*)(ws + 60030976);

  cvt_all<<<10368, 256, 0, stream>>>(x, Wq, Wk, Wv, Wp, xb, wqb, wkb, wvb, wpb);
  gemm_qkv<<<dim3(8, 52, 3), 256, 0, stream>>>(xb, wqb, wkb, wvb, bq, bk, bv, qb, kb, vtb);
  attn<<<dim3(13, 64), 256, 0, stream>>>(qb, kb, vtb, ctxb);
  gemm_out<<<dim3(8, 49), 256, 0, stream>>>(ctxb, wpb, bp, out);
}